// Round 9
// baseline (327.726 us; speedup 1.0000x reference)
//
#include <hip/hip_runtime.h>

// ---------------------------------------------------------------------------
// Fused GAT module, fp16 MFMA (16x16x32). R9: PERSISTENT BLOCKS.
// R8 diagnosis: L3-hot replays still ~100us with all pipes idle -> block
// churn (2048 short blocks, each paying 40KB stage + barrier + ramp).
// Now 768 blocks (3/CU), each stages weights ONCE into LDS then grid-strides
// waves over items (~2.7 items/wave). Epilogue weights (Wvo, Wa_nbr, bvo)
// are folded into the staged region so per-item reads are LDS.
// Carried: value path algebraically folded (out = wI @ (Wv@Wo) + (bv@Wo+bo)),
// weights block-shared in LDS, obs direct global->reg align-4 dwordx4,
// b1 folded into W1 col 83, rcp divides, no softmax max-sub (|e| bounded).
//
// Layout facts used (HW-verified per guide):
//   A-frag: lane l holds A[row = l&15][k = slot(l>>4, i)]
//   B-frag: lane l holds B[k = slot(l>>4, i)][col = l&15]
//   D:      lane l, reg r holds D[4*(l>>4)+r][l&15]
// slot() identical for A and B, so any consistent per-(group,i) k-map works.
// ---------------------------------------------------------------------------

typedef _Float16 half8 __attribute__((ext_vector_type(8)));
typedef __fp16 fp16x2 __attribute__((ext_vector_type(2)));
typedef __fp16 fp16x8 __attribute__((ext_vector_type(8)));
typedef float f32x4 __attribute__((ext_vector_type(4)));

// packed+aligned(4) wrapper: lets the backend emit dwordx4 at 4B alignment
struct __attribute__((packed, aligned(4))) F4 { f32x4 v; };

__device__ __forceinline__ f32x4 ld4(const float* p) {
    return ((const F4*)p)->v;
}

#define MFMA16(a, b, c) __builtin_amdgcn_mfma_f32_16x16x32_f16((a), (b), (c), 0, 0, 0)

// workspace byte offsets (all 16B aligned).
// [0, 49216) is the main-kernel staged region (one linear copy):
#define WS_W1F   0        // 8*3*64*8 half  = 24576 B
#define WS_W2F   24576    // 4*4*64*8 half  = 16384 B
#define WS_WVOF  40960    // 64*16 f32      =  4096 B  (Wv@Wo, frag-ordered)
#define WS_WAFN  45056    // 64*16 f32      =  4096 B
#define WS_BVO   49152    // 16 f32 (+pad)  =    64 B
#define WS_STAGE 49216    // staged bytes (== 3076 f32x4)
// outside staged region:
#define WS_WASF  49216    // 64*16 f32      =  4096 B (self kernel only)
#define WS_ES    53312    // 16384 f32      = 65536 B

__device__ __forceinline__ half8 pack8(float a0, float a1, float a2, float a3,
                                       float a4, float a5, float a6, float a7) {
    fp16x2 p0 = __builtin_amdgcn_cvt_pkrtz(a0, a1);
    fp16x2 p1 = __builtin_amdgcn_cvt_pkrtz(a2, a3);
    fp16x2 p2 = __builtin_amdgcn_cvt_pkrtz(a4, a5);
    fp16x2 p3 = __builtin_amdgcn_cvt_pkrtz(a6, a7);
    fp16x8 h;
    h[0] = p0[0]; h[1] = p0[1]; h[2] = p1[0]; h[3] = p1[1];
    h[4] = p2[0]; h[5] = p2[1]; h[6] = p3[0]; h[7] = p3[1];
    return __builtin_bit_cast(half8, h);
}

// ---------------------------------------------------------------------------
// Prep: frag-ordered fp16 weights + folded fp32 epilogue weights.
// Threads used: 23568 (grid 93 x 256).
// ---------------------------------------------------------------------------
__global__ void prep_kernel(const float* __restrict__ W1, const float* __restrict__ b1,
                            const float* __restrict__ W2, const float* __restrict__ Wv,
                            const float* __restrict__ Wa, const float* __restrict__ Wo,
                            const float* __restrict__ bv, const float* __restrict__ bo,
                            char* __restrict__ ws) {
    int t = blockIdx.x * 256 + threadIdx.x;
    _Float16* W1f = (_Float16*)(ws + WS_W1F);
    _Float16* W2f = (_Float16*)(ws + WS_W2F);
    float* Wvof = (float*)(ws + WS_WVOF);
    float* Wafn = (float*)(ws + WS_WAFN);
    float* Wasf = (float*)(ws + WS_WASF);
    float* bvo  = (float*)(ws + WS_BVO);

    if (t < 12288) {
        // W1f[hm][kt][lane][i] = W1^T[16hm+m][32kt+8g+i]; k==83 carries b1
        int i = t & 7, lane = (t >> 3) & 63, rest = t >> 9;
        int kt = rest % 3, hm = rest / 3;
        int g = lane >> 4, m = lane & 15;
        int k = 32 * kt + 8 * g + i, h = 16 * hm + m;
        float v = (k < 83) ? W1[k * 128 + h] : (k == 83 ? b1[h] : 0.f);
        W1f[t] = (_Float16)v;
    } else if (t < 20480) {
        // W2f[om][kt][lane][i] = W2[h(kt,g,i)][16om+m], h matches acc1 layout
        int u = t - 12288;
        int i = u & 7, lane = (u >> 3) & 63, rest = u >> 9;
        int kt = rest & 3, om = rest >> 2;
        int g = lane >> 4, m = lane & 15;
        int h = 16 * (2 * kt + (i >> 2)) + 4 * g + (i & 3);
        W2f[u] = (_Float16)W2[h * 64 + 16 * om + m];
    } else if (t < 21504) {
        // Wvof[lane][idx] = (Wv@Wo)[o(idx,g)][m], fp32
        int u = t - 20480; int lane = u >> 4, idx = u & 15;
        int g = lane >> 4, m = lane & 15;
        int o = 16 * (idx >> 2) + 4 * g + (idx & 3);
        float acc = 0.f;
#pragma unroll 8
        for (int k = 0; k < 64; ++k) acc += Wv[o * 64 + k] * Wo[k * 16 + m];
        Wvof[u] = acc;
    } else if (t < 22528) {
        int u = t - 21504; int lane = u >> 4, idx = u & 15;
        int g = lane >> 4;
        int o = 16 * (idx >> 2) + 4 * g + (idx & 3);
        Wafn[u] = Wa[64 + o];
    } else if (t < 23552) {
        int u = t - 22528; int lane = u >> 4, idx = u & 15;
        int g = lane >> 4;
        int o = 16 * (idx >> 2) + 4 * g + (idx & 3);
        Wasf[u] = Wa[o];
    } else if (t < 23568) {
        int u = t - 23552;            // bvo[j] = bv@Wo + bo
        float s = bo[u];
#pragma unroll 8
        for (int k = 0; k < 64; ++k) s += bv[k] * Wo[k * 16 + u];
        bvo[u] = s;
    }
}

// ---------------------------------------------------------------------------
// Encode 32 rows (global, contiguous, row stride 83 f32) -> I[om][rn][r].
// Weights from LDS. Lane (g,m) holds I[row = 16rn + m][o = 16om + 4g + r].
// ---------------------------------------------------------------------------
__device__ __forceinline__ void encode32d(const float* __restrict__ src,
                                          const char* wlds,
                                          const float* __restrict__ b2,
                                          int lane, float I[4][2][4]) {
    const half8* W1f = (const half8*)(wlds + WS_W1F);
    const half8* W2f = (const half8*)(wlds + WS_W2F);
    int g = lane >> 4, m = lane & 15;
    const f32x4 zz = {0.f, 0.f, 0.f, 0.f};

    // X^T B-frags straight from global (align-4 dwordx4 slices)
    half8 xf[2][3];
#pragma unroll
    for (int rn = 0; rn < 2; ++rn) {
        const float* rp = src + (16 * rn + m) * 83;
#pragma unroll
        for (int kt = 0; kt < 2; ++kt) {
            f32x4 a = ld4(rp + 32 * kt + 8 * g);
            f32x4 c = ld4(rp + 32 * kt + 8 * g + 4);
            xf[rn][kt] = pack8(a[0], a[1], a[2], a[3], c[0], c[1], c[2], c[3]);
        }
        half8 h;
        if (g < 2) {                          // k = 64+8g .. 71+8g  (<= 79)
            f32x4 a = ld4(rp + 64 + 8 * g);
            f32x4 c = ld4(rp + 68 + 8 * g);
            h = pack8(a[0], a[1], a[2], a[3], c[0], c[1], c[2], c[3]);
        } else if (g == 2) {                  // k = 80,81,82, bias-1, 0...
            h = pack8(rp[80], rp[81], rp[82], 1.f, 0.f, 0.f, 0.f, 0.f);
        } else {                              // k = 88..95: zero pad
            h = pack8(0.f, 0.f, 0.f, 0.f, 0.f, 0.f, 0.f, 0.f);
        }
        xf[rn][2] = h;
    }

    // Layer 1 per hm-pair with scoped accumulators; relu+pack immediately.
    half8 hf[4][2];
#pragma unroll
    for (int t = 0; t < 4; ++t) {
        int h0 = 2 * t, h1 = 2 * t + 1;
        half8 u0 = W1f[(h0 * 3 + 0) * 64 + lane];
        half8 u1 = W1f[(h0 * 3 + 1) * 64 + lane];
        half8 u2 = W1f[(h0 * 3 + 2) * 64 + lane];
        half8 v0 = W1f[(h1 * 3 + 0) * 64 + lane];
        half8 v1 = W1f[(h1 * 3 + 1) * 64 + lane];
        half8 v2 = W1f[(h1 * 3 + 2) * 64 + lane];
#pragma unroll
        for (int rn = 0; rn < 2; ++rn) {
            f32x4 a = zz, b = zz;
            a = MFMA16(u0, xf[rn][0], a);
            a = MFMA16(u1, xf[rn][1], a);
            a = MFMA16(u2, xf[rn][2], a);
            b = MFMA16(v0, xf[rn][0], b);
            b = MFMA16(v1, xf[rn][1], b);
            b = MFMA16(v2, xf[rn][2], b);
            hf[t][rn] = pack8(
                fmaxf(a[0], 0.f), fmaxf(a[1], 0.f), fmaxf(a[2], 0.f), fmaxf(a[3], 0.f),
                fmaxf(b[0], 0.f), fmaxf(b[1], 0.f), fmaxf(b[2], 0.f), fmaxf(b[3], 0.f));
        }
    }

    // Layer 2 per om; bias + tanh straight to I.
#pragma unroll
    for (int om = 0; om < 4; ++om) {
        half8 w0 = W2f[(om * 4 + 0) * 64 + lane];
        half8 w1 = W2f[(om * 4 + 1) * 64 + lane];
        half8 w2 = W2f[(om * 4 + 2) * 64 + lane];
        half8 w3 = W2f[(om * 4 + 3) * 64 + lane];
        float b2v[4];
#pragma unroll
        for (int r = 0; r < 4; ++r) b2v[r] = b2[16 * om + 4 * g + r];
#pragma unroll
        for (int rn = 0; rn < 2; ++rn) {
            f32x4 a = zz;
            a = MFMA16(w0, hf[0][rn], a);
            a = MFMA16(w1, hf[1][rn], a);
            a = MFMA16(w2, hf[2][rn], a);
            a = MFMA16(w3, hf[3][rn], a);
#pragma unroll
            for (int r = 0; r < 4; ++r) {
                float y = a[r] + b2v[r];
                float e = __expf(2.f * y);
                I[om][rn][r] = fmaf(-2.f, __builtin_amdgcn_rcpf(e + 1.f), 1.f);
            }
        }
    }
}

// ---------------------------------------------------------------------------
// Self kernel: es[b] = dot(encode(self_obs[b]), Wa_self). 8 waves/block,
// each wave encodes 32 self rows. Stages only W1f+W2f (40960 B).
// ---------------------------------------------------------------------------
__global__ void __launch_bounds__(512, 3)
self_kernel(const float* __restrict__ sobs,
            const float* __restrict__ b2,
            char* __restrict__ ws) {
    __shared__ __align__(16) char wlds[40960];
    int tid = threadIdx.x, w = tid >> 6, lane = tid & 63;
    int r0 = (blockIdx.x * 8 + w) * 32;

    {
        const f32x4* s4 = (const f32x4*)ws;
        f32x4* d4 = (f32x4*)wlds;
#pragma unroll
        for (int t = 0; t < 5; ++t) d4[t * 512 + tid] = s4[t * 512 + tid];
        __syncthreads();
    }

    float I[4][2][4];
    encode32d(sobs + (size_t)r0 * 83, wlds, b2, lane, I);

    const float* Wasf = (const float*)(ws + WS_WASF);
    float* es = (float*)(ws + WS_ES);

    float was[16];
#pragma unroll
    for (int idx = 0; idx < 16; ++idx) was[idx] = Wasf[lane * 16 + idx];

    float d0 = 0.f, d1 = 0.f;
#pragma unroll
    for (int om = 0; om < 4; ++om)
#pragma unroll
        for (int r = 0; r < 4; ++r) {
            d0 = fmaf(I[om][0][r], was[om * 4 + r], d0);
            d1 = fmaf(I[om][1][r], was[om * 4 + r], d1);
        }
    d0 += __shfl_xor(d0, 16); d0 += __shfl_xor(d0, 32);
    d1 += __shfl_xor(d1, 16); d1 += __shfl_xor(d1, 32);

    if (lane < 16) {
        es[r0 + lane] = d0;
        es[r0 + 16 + lane] = d1;
    }
}

// ---------------------------------------------------------------------------
// Main kernel: PERSISTENT. 768 blocks (3/CU) x 512 thr; stage 49216B once;
// each wave grid-strides items b = wgid, wgid+6144, wgid+12288.
// ---------------------------------------------------------------------------
#define NWAVES 6144

__global__ void __launch_bounds__(512, 6)
main_kernel(const float* __restrict__ nbr,
            const float* __restrict__ edgew,
            const float* __restrict__ b2,
            const float* __restrict__ ba,
            const char* __restrict__ ws,
            float* __restrict__ out) {
    __shared__ __align__(16) char wlds[WS_STAGE];
    int tid = threadIdx.x, w = tid >> 6, lane = tid & 63;
    int wgid = blockIdx.x * 8 + w;
    int g = lane >> 4, m = lane & 15;

    {
        const f32x4* s4 = (const f32x4*)ws;
        f32x4* d4 = (f32x4*)wlds;
#pragma unroll
        for (int t = 0; t < 6; ++t) d4[t * 512 + tid] = s4[t * 512 + tid];
        if (tid < 4) d4[3072 + tid] = s4[3072 + tid];
        __syncthreads();
    }

    const float* es   = (const float*)(ws + WS_ES);
    const float* Wafn = (const float*)(wlds + WS_WAFN);
    const float* Wvof = (const float*)(wlds + WS_WVOF);
    const float* bvo  = (const float*)(wlds + WS_BVO);
    float bav = ba[0];

    for (int b = wgid; b < 16384; b += NWAVES) {
        float esb = es[b];                       // issue early
        float ew0 = edgew[b * 32 + m];
        float ew1 = edgew[b * 32 + 16 + m];

        float I[4][2][4];
        encode32d(nbr + (size_t)b * 2656, wlds, b2, lane, I);

        // attention logits: en[row] = dot(I[row], Wa_nbr)  (Wa_nbr from LDS)
        float en0 = 0.f, en1 = 0.f;
#pragma unroll
        for (int om = 0; om < 4; ++om)
#pragma unroll
            for (int r = 0; r < 4; ++r) {
                float wa = Wafn[lane * 16 + om * 4 + r];
                en0 = fmaf(I[om][0][r], wa, en0);
                en1 = fmaf(I[om][1][r], wa, en1);
            }
        en0 += __shfl_xor(en0, 16); en0 += __shfl_xor(en0, 32);
        en1 += __shfl_xor(en1, 16); en1 += __shfl_xor(en1, 32);

        float e0 = esb + en0 + bav; e0 = (e0 > 0.f) ? e0 : 0.2f * e0; e0 *= ew0;
        float e1 = esb + en1 + bav; e1 = (e1 > 0.f) ? e1 : 0.2f * e1; e1 *= ew1;

        // softmax over 32 neighbors; |e| bounded (~7) -> fp32-safe w/o max-sub
        float p0 = __expf(e0), p1 = __expf(e1);
        float s = p0 + p1;
#pragma unroll
        for (int msk = 1; msk <= 8; msk <<= 1) s += __shfl_xor(s, msk);
        float inv = __builtin_amdgcn_rcpf(s);
        float a0 = p0 * inv, a1 = p1 * inv;

        // weighted intent wI[o] = sum_n alpha_n I[n][o] (fp32, m-lane reduce)
        float wi[16];
#pragma unroll
        for (int om = 0; om < 4; ++om)
#pragma unroll
            for (int r = 0; r < 4; ++r)
                wi[om * 4 + r] = a0 * I[om][0][r] + a1 * I[om][1][r];
#pragma unroll
        for (int idx = 0; idx < 16; ++idx) {
#pragma unroll
            for (int msk = 1; msk <= 8; msk <<= 1)
                wi[idx] += __shfl_xor(wi[idx], msk);
        }

        // out[b][j]: lane (g,m) dots its o-subset for j=m, then g-reduce
        float val = 0.f;
#pragma unroll
        for (int idx = 0; idx < 16; ++idx)
            val = fmaf(wi[idx], Wvof[lane * 16 + idx], val);
        val += __shfl_xor(val, 16);
        val += __shfl_xor(val, 32);

        if (lane < 16) out[(size_t)b * 16 + lane] = val + bvo[lane];
    }
}

// ---------------------------------------------------------------------------
extern "C" void kernel_launch(void* const* d_in, const int* in_sizes, int n_in,
                              void* d_out, int out_size, void* d_ws, size_t ws_size,
                              hipStream_t stream) {
    const float* self_obs = (const float*)d_in[0];
    const float* nbr      = (const float*)d_in[1];
    const float* ew       = (const float*)d_in[2];
    const float* W1       = (const float*)d_in[3];
    const float* b1       = (const float*)d_in[4];
    const float* W2       = (const float*)d_in[5];
    const float* b2       = (const float*)d_in[6];
    const float* Wa       = (const float*)d_in[7];
    const float* ba       = (const float*)d_in[8];
    const float* Wv       = (const float*)d_in[9];
    const float* bv       = (const float*)d_in[10];
    const float* Wo       = (const float*)d_in[11];
    const float* bo       = (const float*)d_in[12];
    char* ws = (char*)d_ws;
    float* out = (float*)d_out;

    prep_kernel<<<93, 256, 0, stream>>>(W1, b1, W2, Wv, Wa, Wo, bv, bo, ws);
    self_kernel<<<64, 512, 0, stream>>>(self_obs, b2, ws);
    main_kernel<<<768, 512, 0, stream>>>(nbr, ew, b2, ba, ws, out);
}

// Round 10
// 171.295 us; speedup vs baseline: 1.9132x; 1.9132x over previous
//
#include <hip/hip_runtime.h>

// ---------------------------------------------------------------------------
// Fused GAT module, fp16 MFMA (16x16x32). R10 = R9 persistent structure with
// the spill fixed: launch_bounds back to (512,3) (R7/R8-proven, 68 VGPR) and
// grid sized to the VGPR occupancy tier: 68 VGPR -> 16 waves/CU -> exactly
// 2 blocks/CU -> 512 persistent blocks, each wave does 4 items (stride 4096).
// Each block stages the 49216B weight region into LDS ONCE, then loops.
// Carried: value path algebraically folded (out = wI @ (Wv@Wo) + (bv@Wo+bo)),
// obs direct global->reg align-4 dwordx4, b1 folded into W1 col 83,
// rcp divides, no softmax max-sub (|e| bounded).
//
// Layout facts used (HW-verified per guide):
//   A-frag: lane l holds A[row = l&15][k = slot(l>>4, i)]
//   B-frag: lane l holds B[k = slot(l>>4, i)][col = l&15]
//   D:      lane l, reg r holds D[4*(l>>4)+r][l&15]
// slot() identical for A and B, so any consistent per-(group,i) k-map works.
// ---------------------------------------------------------------------------

typedef _Float16 half8 __attribute__((ext_vector_type(8)));
typedef __fp16 fp16x2 __attribute__((ext_vector_type(2)));
typedef __fp16 fp16x8 __attribute__((ext_vector_type(8)));
typedef float f32x4 __attribute__((ext_vector_type(4)));

// packed+aligned(4) wrapper: lets the backend emit dwordx4 at 4B alignment
struct __attribute__((packed, aligned(4))) F4 { f32x4 v; };

__device__ __forceinline__ f32x4 ld4(const float* p) {
    return ((const F4*)p)->v;
}

#define MFMA16(a, b, c) __builtin_amdgcn_mfma_f32_16x16x32_f16((a), (b), (c), 0, 0, 0)

// workspace byte offsets (all 16B aligned).
// [0, 49216) is the main-kernel staged region (one linear copy):
#define WS_W1F   0        // 8*3*64*8 half  = 24576 B
#define WS_W2F   24576    // 4*4*64*8 half  = 16384 B
#define WS_WVOF  40960    // 64*16 f32      =  4096 B  (Wv@Wo, frag-ordered)
#define WS_WAFN  45056    // 64*16 f32      =  4096 B
#define WS_BVO   49152    // 16 f32 (+pad)  =    64 B
#define WS_STAGE 49216    // staged bytes (== 3076 f32x4)
// outside staged region:
#define WS_WASF  49216    // 64*16 f32      =  4096 B (self kernel only)
#define WS_ES    53312    // 16384 f32      = 65536 B

__device__ __forceinline__ half8 pack8(float a0, float a1, float a2, float a3,
                                       float a4, float a5, float a6, float a7) {
    fp16x2 p0 = __builtin_amdgcn_cvt_pkrtz(a0, a1);
    fp16x2 p1 = __builtin_amdgcn_cvt_pkrtz(a2, a3);
    fp16x2 p2 = __builtin_amdgcn_cvt_pkrtz(a4, a5);
    fp16x2 p3 = __builtin_amdgcn_cvt_pkrtz(a6, a7);
    fp16x8 h;
    h[0] = p0[0]; h[1] = p0[1]; h[2] = p1[0]; h[3] = p1[1];
    h[4] = p2[0]; h[5] = p2[1]; h[6] = p3[0]; h[7] = p3[1];
    return __builtin_bit_cast(half8, h);
}

// ---------------------------------------------------------------------------
// Prep: frag-ordered fp16 weights + folded fp32 epilogue weights.
// Threads used: 23568 (grid 93 x 256).
// ---------------------------------------------------------------------------
__global__ void prep_kernel(const float* __restrict__ W1, const float* __restrict__ b1,
                            const float* __restrict__ W2, const float* __restrict__ Wv,
                            const float* __restrict__ Wa, const float* __restrict__ Wo,
                            const float* __restrict__ bv, const float* __restrict__ bo,
                            char* __restrict__ ws) {
    int t = blockIdx.x * 256 + threadIdx.x;
    _Float16* W1f = (_Float16*)(ws + WS_W1F);
    _Float16* W2f = (_Float16*)(ws + WS_W2F);
    float* Wvof = (float*)(ws + WS_WVOF);
    float* Wafn = (float*)(ws + WS_WAFN);
    float* Wasf = (float*)(ws + WS_WASF);
    float* bvo  = (float*)(ws + WS_BVO);

    if (t < 12288) {
        // W1f[hm][kt][lane][i] = W1^T[16hm+m][32kt+8g+i]; k==83 carries b1
        int i = t & 7, lane = (t >> 3) & 63, rest = t >> 9;
        int kt = rest % 3, hm = rest / 3;
        int g = lane >> 4, m = lane & 15;
        int k = 32 * kt + 8 * g + i, h = 16 * hm + m;
        float v = (k < 83) ? W1[k * 128 + h] : (k == 83 ? b1[h] : 0.f);
        W1f[t] = (_Float16)v;
    } else if (t < 20480) {
        // W2f[om][kt][lane][i] = W2[h(kt,g,i)][16om+m], h matches acc1 layout
        int u = t - 12288;
        int i = u & 7, lane = (u >> 3) & 63, rest = u >> 9;
        int kt = rest & 3, om = rest >> 2;
        int g = lane >> 4, m = lane & 15;
        int h = 16 * (2 * kt + (i >> 2)) + 4 * g + (i & 3);
        W2f[u] = (_Float16)W2[h * 64 + 16 * om + m];
    } else if (t < 21504) {
        // Wvof[lane][idx] = (Wv@Wo)[o(idx,g)][m], fp32
        int u = t - 20480; int lane = u >> 4, idx = u & 15;
        int g = lane >> 4, m = lane & 15;
        int o = 16 * (idx >> 2) + 4 * g + (idx & 3);
        float acc = 0.f;
#pragma unroll 8
        for (int k = 0; k < 64; ++k) acc += Wv[o * 64 + k] * Wo[k * 16 + m];
        Wvof[u] = acc;
    } else if (t < 22528) {
        int u = t - 21504; int lane = u >> 4, idx = u & 15;
        int g = lane >> 4;
        int o = 16 * (idx >> 2) + 4 * g + (idx & 3);
        Wafn[u] = Wa[64 + o];
    } else if (t < 23552) {
        int u = t - 22528; int lane = u >> 4, idx = u & 15;
        int g = lane >> 4;
        int o = 16 * (idx >> 2) + 4 * g + (idx & 3);
        Wasf[u] = Wa[o];
    } else if (t < 23568) {
        int u = t - 23552;            // bvo[j] = bv@Wo + bo
        float s = bo[u];
#pragma unroll 8
        for (int k = 0; k < 64; ++k) s += bv[k] * Wo[k * 16 + u];
        bvo[u] = s;
    }
}

// ---------------------------------------------------------------------------
// Encode 32 rows (global, contiguous, row stride 83 f32) -> I[om][rn][r].
// Weights from LDS. Lane (g,m) holds I[row = 16rn + m][o = 16om + 4g + r].
// ---------------------------------------------------------------------------
__device__ __forceinline__ void encode32d(const float* __restrict__ src,
                                          const char* wlds,
                                          const float* __restrict__ b2,
                                          int lane, float I[4][2][4]) {
    const half8* W1f = (const half8*)(wlds + WS_W1F);
    const half8* W2f = (const half8*)(wlds + WS_W2F);
    int g = lane >> 4, m = lane & 15;
    const f32x4 zz = {0.f, 0.f, 0.f, 0.f};

    // X^T B-frags straight from global (align-4 dwordx4 slices)
    half8 xf[2][3];
#pragma unroll
    for (int rn = 0; rn < 2; ++rn) {
        const float* rp = src + (16 * rn + m) * 83;
#pragma unroll
        for (int kt = 0; kt < 2; ++kt) {
            f32x4 a = ld4(rp + 32 * kt + 8 * g);
            f32x4 c = ld4(rp + 32 * kt + 8 * g + 4);
            xf[rn][kt] = pack8(a[0], a[1], a[2], a[3], c[0], c[1], c[2], c[3]);
        }
        half8 h;
        if (g < 2) {                          // k = 64+8g .. 71+8g  (<= 79)
            f32x4 a = ld4(rp + 64 + 8 * g);
            f32x4 c = ld4(rp + 68 + 8 * g);
            h = pack8(a[0], a[1], a[2], a[3], c[0], c[1], c[2], c[3]);
        } else if (g == 2) {                  // k = 80,81,82, bias-1, 0...
            h = pack8(rp[80], rp[81], rp[82], 1.f, 0.f, 0.f, 0.f, 0.f);
        } else {                              // k = 88..95: zero pad
            h = pack8(0.f, 0.f, 0.f, 0.f, 0.f, 0.f, 0.f, 0.f);
        }
        xf[rn][2] = h;
    }

    // Layer 1 per hm-pair with scoped accumulators; relu+pack immediately.
    half8 hf[4][2];
#pragma unroll
    for (int t = 0; t < 4; ++t) {
        int h0 = 2 * t, h1 = 2 * t + 1;
        half8 u0 = W1f[(h0 * 3 + 0) * 64 + lane];
        half8 u1 = W1f[(h0 * 3 + 1) * 64 + lane];
        half8 u2 = W1f[(h0 * 3 + 2) * 64 + lane];
        half8 v0 = W1f[(h1 * 3 + 0) * 64 + lane];
        half8 v1 = W1f[(h1 * 3 + 1) * 64 + lane];
        half8 v2 = W1f[(h1 * 3 + 2) * 64 + lane];
#pragma unroll
        for (int rn = 0; rn < 2; ++rn) {
            f32x4 a = zz, b = zz;
            a = MFMA16(u0, xf[rn][0], a);
            a = MFMA16(u1, xf[rn][1], a);
            a = MFMA16(u2, xf[rn][2], a);
            b = MFMA16(v0, xf[rn][0], b);
            b = MFMA16(v1, xf[rn][1], b);
            b = MFMA16(v2, xf[rn][2], b);
            hf[t][rn] = pack8(
                fmaxf(a[0], 0.f), fmaxf(a[1], 0.f), fmaxf(a[2], 0.f), fmaxf(a[3], 0.f),
                fmaxf(b[0], 0.f), fmaxf(b[1], 0.f), fmaxf(b[2], 0.f), fmaxf(b[3], 0.f));
        }
    }

    // Layer 2 per om; bias + tanh straight to I.
#pragma unroll
    for (int om = 0; om < 4; ++om) {
        half8 w0 = W2f[(om * 4 + 0) * 64 + lane];
        half8 w1 = W2f[(om * 4 + 1) * 64 + lane];
        half8 w2 = W2f[(om * 4 + 2) * 64 + lane];
        half8 w3 = W2f[(om * 4 + 3) * 64 + lane];
        float b2v[4];
#pragma unroll
        for (int r = 0; r < 4; ++r) b2v[r] = b2[16 * om + 4 * g + r];
#pragma unroll
        for (int rn = 0; rn < 2; ++rn) {
            f32x4 a = zz;
            a = MFMA16(w0, hf[0][rn], a);
            a = MFMA16(w1, hf[1][rn], a);
            a = MFMA16(w2, hf[2][rn], a);
            a = MFMA16(w3, hf[3][rn], a);
#pragma unroll
            for (int r = 0; r < 4; ++r) {
                float y = a[r] + b2v[r];
                float e = __expf(2.f * y);
                I[om][rn][r] = fmaf(-2.f, __builtin_amdgcn_rcpf(e + 1.f), 1.f);
            }
        }
    }
}

// ---------------------------------------------------------------------------
// Self kernel: es[b] = dot(encode(self_obs[b]), Wa_self). 8 waves/block,
// each wave encodes 32 self rows. Stages only W1f+W2f (40960 B).
// ---------------------------------------------------------------------------
__global__ void __launch_bounds__(512, 3)
self_kernel(const float* __restrict__ sobs,
            const float* __restrict__ b2,
            char* __restrict__ ws) {
    __shared__ __align__(16) char wlds[40960];
    int tid = threadIdx.x, w = tid >> 6, lane = tid & 63;
    int r0 = (blockIdx.x * 8 + w) * 32;

    {
        const f32x4* s4 = (const f32x4*)ws;
        f32x4* d4 = (f32x4*)wlds;
#pragma unroll
        for (int t = 0; t < 5; ++t) d4[t * 512 + tid] = s4[t * 512 + tid];
        __syncthreads();
    }

    float I[4][2][4];
    encode32d(sobs + (size_t)r0 * 83, wlds, b2, lane, I);

    const float* Wasf = (const float*)(ws + WS_WASF);
    float* es = (float*)(ws + WS_ES);

    float was[16];
#pragma unroll
    for (int idx = 0; idx < 16; ++idx) was[idx] = Wasf[lane * 16 + idx];

    float d0 = 0.f, d1 = 0.f;
#pragma unroll
    for (int om = 0; om < 4; ++om)
#pragma unroll
        for (int r = 0; r < 4; ++r) {
            d0 = fmaf(I[om][0][r], was[om * 4 + r], d0);
            d1 = fmaf(I[om][1][r], was[om * 4 + r], d1);
        }
    d0 += __shfl_xor(d0, 16); d0 += __shfl_xor(d0, 32);
    d1 += __shfl_xor(d1, 16); d1 += __shfl_xor(d1, 32);

    if (lane < 16) {
        es[r0 + lane] = d0;
        es[r0 + 16 + lane] = d1;
    }
}

// ---------------------------------------------------------------------------
// Main kernel: PERSISTENT. 512 blocks (2/CU, matching the 16-waves/CU VGPR
// tier) x 512 thr; stage 49216B once; each wave does 4 items (stride 4096).
// ---------------------------------------------------------------------------
#define NWAVES 4096

__global__ void __launch_bounds__(512, 3)
main_kernel(const float* __restrict__ nbr,
            const float* __restrict__ edgew,
            const float* __restrict__ b2,
            const float* __restrict__ ba,
            const char* __restrict__ ws,
            float* __restrict__ out) {
    __shared__ __align__(16) char wlds[WS_STAGE];
    int tid = threadIdx.x, w = tid >> 6, lane = tid & 63;
    int wgid = blockIdx.x * 8 + w;
    int g = lane >> 4, m = lane & 15;

    {
        const f32x4* s4 = (const f32x4*)ws;
        f32x4* d4 = (f32x4*)wlds;
#pragma unroll
        for (int t = 0; t < 6; ++t) d4[t * 512 + tid] = s4[t * 512 + tid];
        if (tid < 4) d4[3072 + tid] = s4[3072 + tid];
        __syncthreads();
    }

    const float* es   = (const float*)(ws + WS_ES);
    const float* Wafn = (const float*)(wlds + WS_WAFN);
    const float* Wvof = (const float*)(wlds + WS_WVOF);
    const float* bvo  = (const float*)(wlds + WS_BVO);
    float bav = ba[0];

    for (int b = wgid; b < 16384; b += NWAVES) {
        float esb = es[b];                       // issue early
        float ew0 = edgew[b * 32 + m];
        float ew1 = edgew[b * 32 + 16 + m];

        float I[4][2][4];
        encode32d(nbr + (size_t)b * 2656, wlds, b2, lane, I);

        // attention logits: en[row] = dot(I[row], Wa_nbr)  (Wa_nbr from LDS)
        float en0 = 0.f, en1 = 0.f;
#pragma unroll
        for (int om = 0; om < 4; ++om)
#pragma unroll
            for (int r = 0; r < 4; ++r) {
                float wa = Wafn[lane * 16 + om * 4 + r];
                en0 = fmaf(I[om][0][r], wa, en0);
                en1 = fmaf(I[om][1][r], wa, en1);
            }
        en0 += __shfl_xor(en0, 16); en0 += __shfl_xor(en0, 32);
        en1 += __shfl_xor(en1, 16); en1 += __shfl_xor(en1, 32);

        float e0 = esb + en0 + bav; e0 = (e0 > 0.f) ? e0 : 0.2f * e0; e0 *= ew0;
        float e1 = esb + en1 + bav; e1 = (e1 > 0.f) ? e1 : 0.2f * e1; e1 *= ew1;

        // softmax over 32 neighbors; |e| bounded (~7) -> fp32-safe w/o max-sub
        float p0 = __expf(e0), p1 = __expf(e1);
        float s = p0 + p1;
#pragma unroll
        for (int msk = 1; msk <= 8; msk <<= 1) s += __shfl_xor(s, msk);
        float inv = __builtin_amdgcn_rcpf(s);
        float a0 = p0 * inv, a1 = p1 * inv;

        // weighted intent wI[o] = sum_n alpha_n I[n][o] (fp32, m-lane reduce)
        float wi[16];
#pragma unroll
        for (int om = 0; om < 4; ++om)
#pragma unroll
            for (int r = 0; r < 4; ++r)
                wi[om * 4 + r] = a0 * I[om][0][r] + a1 * I[om][1][r];
#pragma unroll
        for (int idx = 0; idx < 16; ++idx) {
#pragma unroll
            for (int msk = 1; msk <= 8; msk <<= 1)
                wi[idx] += __shfl_xor(wi[idx], msk);
        }

        // out[b][j]: lane (g,m) dots its o-subset for j=m, then g-reduce
        float val = 0.f;
#pragma unroll
        for (int idx = 0; idx < 16; ++idx)
            val = fmaf(wi[idx], Wvof[lane * 16 + idx], val);
        val += __shfl_xor(val, 16);
        val += __shfl_xor(val, 32);

        if (lane < 16) out[(size_t)b * 16 + lane] = val + bvo[lane];
    }
}

// ---------------------------------------------------------------------------
extern "C" void kernel_launch(void* const* d_in, const int* in_sizes, int n_in,
                              void* d_out, int out_size, void* d_ws, size_t ws_size,
                              hipStream_t stream) {
    const float* self_obs = (const float*)d_in[0];
    const float* nbr      = (const float*)d_in[1];
    const float* ew       = (const float*)d_in[2];
    const float* W1       = (const float*)d_in[3];
    const float* b1       = (const float*)d_in[4];
    const float* W2       = (const float*)d_in[5];
    const float* b2       = (const float*)d_in[6];
    const float* Wa       = (const float*)d_in[7];
    const float* ba       = (const float*)d_in[8];
    const float* Wv       = (const float*)d_in[9];
    const float* bv       = (const float*)d_in[10];
    const float* Wo       = (const float*)d_in[11];
    const float* bo       = (const float*)d_in[12];
    char* ws = (char*)d_ws;
    float* out = (float*)d_out;

    prep_kernel<<<93, 256, 0, stream>>>(W1, b1, W2, Wv, Wa, Wo, bv, bo, ws);
    self_kernel<<<64, 512, 0, stream>>>(self_obs, b2, ws);
    main_kernel<<<512, 512, 0, stream>>>(nbr, ew, b2, ba, ws, out);
}

// Round 11
// 58.658 us; speedup vs baseline: 5.5871x; 2.9203x over previous
//
#include <hip/hip_runtime.h>

// ---------------------------------------------------------------------------
// Fused GAT module, fp16 MFMA (16x16x32). R11 = R7/R8 structure + T14 async
// obs-load split. Persistent variants (R9/R10) spilled (loop unroll blew the
// unified VGPR/AGPR budget) and are abandoned.
//   - 2048 blocks x 512 thr (8 waves), one item per wave (R7 shape, best wall)
//   - obs global loads ISSUED FIRST into registers, then the 49216B weight
//     region is staged to LDS; the pre-barrier vmcnt(0) drains both in
//     parallel -> obs HBM latency hidden under the stage every block pays.
//   - folded epilogue: out = wI @ (Wv@Wo) + (bv@Wo + bo)  (alpha scalar/item,
//     sums to 1 -> value path commutes with the linears; fp32, fewer MFMAs)
//   - b1 folded into W1 via constant-1 column at k=83; rcp divides; no
//     softmax max-sub (|e| bounded ~7, fp32-safe).
//
// Layout facts used (HW-verified per guide):
//   A-frag: lane l holds A[row = l&15][k = slot(l>>4, i)]
//   B-frag: lane l holds B[k = slot(l>>4, i)][col = l&15]
//   D:      lane l, reg r holds D[4*(l>>4)+r][l&15]
// slot() identical for A and B, so any consistent per-(group,i) k-map works.
// ---------------------------------------------------------------------------

typedef _Float16 half8 __attribute__((ext_vector_type(8)));
typedef __fp16 fp16x2 __attribute__((ext_vector_type(2)));
typedef __fp16 fp16x8 __attribute__((ext_vector_type(8)));
typedef float f32x4 __attribute__((ext_vector_type(4)));

// packed+aligned(4) wrapper: lets the backend emit dwordx4 at 4B alignment
struct __attribute__((packed, aligned(4))) F4 { f32x4 v; };

__device__ __forceinline__ f32x4 ld4(const float* p) {
    return ((const F4*)p)->v;
}

#define MFMA16(a, b, c) __builtin_amdgcn_mfma_f32_16x16x32_f16((a), (b), (c), 0, 0, 0)

// workspace byte offsets (all 16B aligned).
// [0, 49216) is the main-kernel staged region (one linear copy):
#define WS_W1F   0        // 8*3*64*8 half  = 24576 B
#define WS_W2F   24576    // 4*4*64*8 half  = 16384 B
#define WS_WVOF  40960    // 64*16 f32      =  4096 B  (Wv@Wo, frag-ordered)
#define WS_WAFN  45056    // 64*16 f32      =  4096 B
#define WS_BVO   49152    // 16 f32 (+pad)  =    64 B
#define WS_STAGE 49216    // staged bytes (== 3076 f32x4)
// outside staged region:
#define WS_WASF  49216    // 64*16 f32      =  4096 B (self kernel only)
#define WS_ES    53312    // 16384 f32      = 65536 B

__device__ __forceinline__ half8 pack8(float a0, float a1, float a2, float a3,
                                       float a4, float a5, float a6, float a7) {
    fp16x2 p0 = __builtin_amdgcn_cvt_pkrtz(a0, a1);
    fp16x2 p1 = __builtin_amdgcn_cvt_pkrtz(a2, a3);
    fp16x2 p2 = __builtin_amdgcn_cvt_pkrtz(a4, a5);
    fp16x2 p3 = __builtin_amdgcn_cvt_pkrtz(a6, a7);
    fp16x8 h;
    h[0] = p0[0]; h[1] = p0[1]; h[2] = p1[0]; h[3] = p1[1];
    h[4] = p2[0]; h[5] = p2[1]; h[6] = p3[0]; h[7] = p3[1];
    return __builtin_bit_cast(half8, h);
}

// ---------------------------------------------------------------------------
// Prep: frag-ordered fp16 weights + folded fp32 epilogue weights.
// Threads used: 23568 (grid 93 x 256).
// ---------------------------------------------------------------------------
__global__ void prep_kernel(const float* __restrict__ W1, const float* __restrict__ b1,
                            const float* __restrict__ W2, const float* __restrict__ Wv,
                            const float* __restrict__ Wa, const float* __restrict__ Wo,
                            const float* __restrict__ bv, const float* __restrict__ bo,
                            char* __restrict__ ws) {
    int t = blockIdx.x * 256 + threadIdx.x;
    _Float16* W1f = (_Float16*)(ws + WS_W1F);
    _Float16* W2f = (_Float16*)(ws + WS_W2F);
    float* Wvof = (float*)(ws + WS_WVOF);
    float* Wafn = (float*)(ws + WS_WAFN);
    float* Wasf = (float*)(ws + WS_WASF);
    float* bvo  = (float*)(ws + WS_BVO);

    if (t < 12288) {
        // W1f[hm][kt][lane][i] = W1^T[16hm+m][32kt+8g+i]; k==83 carries b1
        int i = t & 7, lane = (t >> 3) & 63, rest = t >> 9;
        int kt = rest % 3, hm = rest / 3;
        int g = lane >> 4, m = lane & 15;
        int k = 32 * kt + 8 * g + i, h = 16 * hm + m;
        float v = (k < 83) ? W1[k * 128 + h] : (k == 83 ? b1[h] : 0.f);
        W1f[t] = (_Float16)v;
    } else if (t < 20480) {
        // W2f[om][kt][lane][i] = W2[h(kt,g,i)][16om+m], h matches acc1 layout
        int u = t - 12288;
        int i = u & 7, lane = (u >> 3) & 63, rest = u >> 9;
        int kt = rest & 3, om = rest >> 2;
        int g = lane >> 4, m = lane & 15;
        int h = 16 * (2 * kt + (i >> 2)) + 4 * g + (i & 3);
        W2f[u] = (_Float16)W2[h * 64 + 16 * om + m];
    } else if (t < 21504) {
        // Wvof[lane][idx] = (Wv@Wo)[o(idx,g)][m], fp32
        int u = t - 20480; int lane = u >> 4, idx = u & 15;
        int g = lane >> 4, m = lane & 15;
        int o = 16 * (idx >> 2) + 4 * g + (idx & 3);
        float acc = 0.f;
#pragma unroll 8
        for (int k = 0; k < 64; ++k) acc += Wv[o * 64 + k] * Wo[k * 16 + m];
        Wvof[u] = acc;
    } else if (t < 22528) {
        int u = t - 21504; int lane = u >> 4, idx = u & 15;
        int g = lane >> 4;
        int o = 16 * (idx >> 2) + 4 * g + (idx & 3);
        Wafn[u] = Wa[64 + o];
    } else if (t < 23552) {
        int u = t - 22528; int lane = u >> 4, idx = u & 15;
        int g = lane >> 4;
        int o = 16 * (idx >> 2) + 4 * g + (idx & 3);
        Wasf[u] = Wa[o];
    } else if (t < 23568) {
        int u = t - 23552;            // bvo[j] = bv@Wo + bo
        float s = bo[u];
#pragma unroll 8
        for (int k = 0; k < 64; ++k) s += bv[k] * Wo[k * 16 + u];
        bvo[u] = s;
    }
}

// ---------------------------------------------------------------------------
// Issue the 12 obs dwordx4 loads for one item (raw registers, no processing).
// Lane (g,m): rows 16rn+m, col slice 8g. g==2 tail uses ld4(rp+79) (in-row,
// elems 79..82) to avoid cross-row/OOB reads; g==3 loads row start (dummy).
// ---------------------------------------------------------------------------
__device__ __forceinline__ void load_raw(const float* __restrict__ src,
                                         int g, int m, f32x4 raw[2][6]) {
#pragma unroll
    for (int rn = 0; rn < 2; ++rn) {
        const float* rp = src + (16 * rn + m) * 83;
        raw[rn][0] = ld4(rp + 8 * g);
        raw[rn][1] = ld4(rp + 8 * g + 4);
        raw[rn][2] = ld4(rp + 32 + 8 * g);
        raw[rn][3] = ld4(rp + 32 + 8 * g + 4);
        const float* p2 = (g < 2) ? (rp + 64 + 8 * g) : (g == 2 ? rp + 79 : rp);
        raw[rn][4] = ld4(p2);
        raw[rn][5] = ld4((g < 2) ? p2 + 4 : p2);
    }
}

// ---------------------------------------------------------------------------
// Convert raw obs registers -> X^T B-frags (bias-1 at k=83, zeros beyond).
// ---------------------------------------------------------------------------
__device__ __forceinline__ void pack_xf(const f32x4 raw[2][6], int g,
                                        half8 xf[2][3]) {
    const half8 hz = {0, 0, 0, 0, 0, 0, 0, 0};
#pragma unroll
    for (int rn = 0; rn < 2; ++rn) {
        xf[rn][0] = pack8(raw[rn][0][0], raw[rn][0][1], raw[rn][0][2], raw[rn][0][3],
                          raw[rn][1][0], raw[rn][1][1], raw[rn][1][2], raw[rn][1][3]);
        xf[rn][1] = pack8(raw[rn][2][0], raw[rn][2][1], raw[rn][2][2], raw[rn][2][3],
                          raw[rn][3][0], raw[rn][3][1], raw[rn][3][2], raw[rn][3][3]);
        half8 h;
        if (g < 2) {
            h = pack8(raw[rn][4][0], raw[rn][4][1], raw[rn][4][2], raw[rn][4][3],
                      raw[rn][5][0], raw[rn][5][1], raw[rn][5][2], raw[rn][5][3]);
        } else if (g == 2) {
            // raw[rn][4] = elems 79,80,81,82 ; k=80..82 + bias-1 at k=83
            h = pack8(raw[rn][4][1], raw[rn][4][2], raw[rn][4][3], 1.f,
                      0.f, 0.f, 0.f, 0.f);
        } else {
            h = hz;
        }
        xf[rn][2] = h;
    }
}

// ---------------------------------------------------------------------------
// MLP from xf frags: layer1 (hm-pair scoped acc, relu+pack) + layer2 + tanh.
// Weights from LDS. Lane (g,m) holds I[row = 16rn + m][o = 16om + 4g + r].
// ---------------------------------------------------------------------------
__device__ __forceinline__ void mlp_from_xf(const half8 xf[2][3],
                                            const char* wlds,
                                            const float* __restrict__ b2,
                                            int lane, int g, float I[4][2][4]) {
    const half8* W1f = (const half8*)(wlds + WS_W1F);
    const half8* W2f = (const half8*)(wlds + WS_W2F);
    const f32x4 zz = {0.f, 0.f, 0.f, 0.f};

    half8 hf[4][2];
#pragma unroll
    for (int t = 0; t < 4; ++t) {
        int h0 = 2 * t, h1 = 2 * t + 1;
        half8 u0 = W1f[(h0 * 3 + 0) * 64 + lane];
        half8 u1 = W1f[(h0 * 3 + 1) * 64 + lane];
        half8 u2 = W1f[(h0 * 3 + 2) * 64 + lane];
        half8 v0 = W1f[(h1 * 3 + 0) * 64 + lane];
        half8 v1 = W1f[(h1 * 3 + 1) * 64 + lane];
        half8 v2 = W1f[(h1 * 3 + 2) * 64 + lane];
#pragma unroll
        for (int rn = 0; rn < 2; ++rn) {
            f32x4 a = zz, b = zz;
            a = MFMA16(u0, xf[rn][0], a);
            a = MFMA16(u1, xf[rn][1], a);
            a = MFMA16(u2, xf[rn][2], a);
            b = MFMA16(v0, xf[rn][0], b);
            b = MFMA16(v1, xf[rn][1], b);
            b = MFMA16(v2, xf[rn][2], b);
            hf[t][rn] = pack8(
                fmaxf(a[0], 0.f), fmaxf(a[1], 0.f), fmaxf(a[2], 0.f), fmaxf(a[3], 0.f),
                fmaxf(b[0], 0.f), fmaxf(b[1], 0.f), fmaxf(b[2], 0.f), fmaxf(b[3], 0.f));
        }
    }

#pragma unroll
    for (int om = 0; om < 4; ++om) {
        half8 w0 = W2f[(om * 4 + 0) * 64 + lane];
        half8 w1 = W2f[(om * 4 + 1) * 64 + lane];
        half8 w2 = W2f[(om * 4 + 2) * 64 + lane];
        half8 w3 = W2f[(om * 4 + 3) * 64 + lane];
        float b2v[4];
#pragma unroll
        for (int r = 0; r < 4; ++r) b2v[r] = b2[16 * om + 4 * g + r];
#pragma unroll
        for (int rn = 0; rn < 2; ++rn) {
            f32x4 a = zz;
            a = MFMA16(w0, hf[0][rn], a);
            a = MFMA16(w1, hf[1][rn], a);
            a = MFMA16(w2, hf[2][rn], a);
            a = MFMA16(w3, hf[3][rn], a);
#pragma unroll
            for (int r = 0; r < 4; ++r) {
                float y = a[r] + b2v[r];
                float e = __expf(2.f * y);
                I[om][rn][r] = fmaf(-2.f, __builtin_amdgcn_rcpf(e + 1.f), 1.f);
            }
        }
    }
}

// ---------------------------------------------------------------------------
// Self kernel: es[b] = dot(encode(self_obs[b]), Wa_self). 8 waves/block,
// async-split obs loads, stages only W1f+W2f (40960 B).
// ---------------------------------------------------------------------------
__global__ void __launch_bounds__(512, 3)
self_kernel(const float* __restrict__ sobs,
            const float* __restrict__ b2,
            char* __restrict__ ws) {
    __shared__ __align__(16) char wlds[40960];
    int tid = threadIdx.x, w = tid >> 6, lane = tid & 63;
    int g = lane >> 4, m = lane & 15;
    int r0 = (blockIdx.x * 8 + w) * 32;

    f32x4 raw[2][6];
    load_raw(sobs + (size_t)r0 * 83, g, m, raw);   // issue before stage

    {
        const f32x4* s4 = (const f32x4*)ws;
        f32x4* d4 = (f32x4*)wlds;
#pragma unroll
        for (int t = 0; t < 5; ++t) d4[t * 512 + tid] = s4[t * 512 + tid];
        __syncthreads();
    }

    half8 xf[2][3];
    pack_xf(raw, g, xf);
    float I[4][2][4];
    mlp_from_xf(xf, wlds, b2, lane, g, I);

    const float* Wasf = (const float*)(ws + WS_WASF);
    float* es = (float*)(ws + WS_ES);

    float was[16];
#pragma unroll
    for (int idx = 0; idx < 16; ++idx) was[idx] = Wasf[lane * 16 + idx];

    float d0 = 0.f, d1 = 0.f;
#pragma unroll
    for (int om = 0; om < 4; ++om)
#pragma unroll
        for (int r = 0; r < 4; ++r) {
            d0 = fmaf(I[om][0][r], was[om * 4 + r], d0);
            d1 = fmaf(I[om][1][r], was[om * 4 + r], d1);
        }
    d0 += __shfl_xor(d0, 16); d0 += __shfl_xor(d0, 32);
    d1 += __shfl_xor(d1, 16); d1 += __shfl_xor(d1, 32);

    if (lane < 16) {
        es[r0 + lane] = d0;
        es[r0 + 16 + lane] = d1;
    }
}

// ---------------------------------------------------------------------------
// Main kernel: 2048 blocks x 512 thr, one item per wave. Async-split:
// obs loads issue first, weight stage second, barrier drains both together.
// ---------------------------------------------------------------------------
__global__ void __launch_bounds__(512, 3)
main_kernel(const float* __restrict__ nbr,
            const float* __restrict__ edgew,
            const float* __restrict__ b2,
            const float* __restrict__ ba,
            const char* __restrict__ ws,
            float* __restrict__ out) {
    __shared__ __align__(16) char wlds[WS_STAGE];
    int tid = threadIdx.x, w = tid >> 6, lane = tid & 63;
    int b = blockIdx.x * 8 + w;
    int g = lane >> 4, m = lane & 15;

    // ---- A: issue all per-item global loads FIRST ----
    f32x4 raw[2][6];
    load_raw(nbr + (size_t)b * 2656, g, m, raw);
    const float* es = (const float*)(ws + WS_ES);
    float esb = es[b];
    float ew0 = edgew[b * 32 + m];
    float ew1 = edgew[b * 32 + 16 + m];
    float bav = ba[0];

    // ---- B: stage weights; barrier drains stage AND obs loads together ----
    {
        const f32x4* s4 = (const f32x4*)ws;
        f32x4* d4 = (f32x4*)wlds;
#pragma unroll
        for (int t = 0; t < 6; ++t) d4[t * 512 + tid] = s4[t * 512 + tid];
        if (tid < 4) d4[3072 + tid] = s4[3072 + tid];
        __syncthreads();
    }

    // ---- C: pack + MLP ----
    half8 xf[2][3];
    pack_xf(raw, g, xf);
    float I[4][2][4];
    mlp_from_xf(xf, wlds, b2, lane, g, I);

    const float* Wafn = (const float*)(wlds + WS_WAFN);
    const float* Wvof = (const float*)(wlds + WS_WVOF);
    const float* bvo  = (const float*)(wlds + WS_BVO);

    // attention logits: en[row] = dot(I[row], Wa_nbr)  (Wa_nbr from LDS)
    float en0 = 0.f, en1 = 0.f;
#pragma unroll
    for (int om = 0; om < 4; ++om)
#pragma unroll
        for (int r = 0; r < 4; ++r) {
            float wa = Wafn[lane * 16 + om * 4 + r];
            en0 = fmaf(I[om][0][r], wa, en0);
            en1 = fmaf(I[om][1][r], wa, en1);
        }
    en0 += __shfl_xor(en0, 16); en0 += __shfl_xor(en0, 32);
    en1 += __shfl_xor(en1, 16); en1 += __shfl_xor(en1, 32);

    float e0 = esb + en0 + bav; e0 = (e0 > 0.f) ? e0 : 0.2f * e0; e0 *= ew0;
    float e1 = esb + en1 + bav; e1 = (e1 > 0.f) ? e1 : 0.2f * e1; e1 *= ew1;

    // softmax over 32 neighbors; |e| bounded (~7) -> fp32-safe w/o max-sub
    float p0 = __expf(e0), p1 = __expf(e1);
    float s = p0 + p1;
#pragma unroll
    for (int msk = 1; msk <= 8; msk <<= 1) s += __shfl_xor(s, msk);
    float inv = __builtin_amdgcn_rcpf(s);
    float a0 = p0 * inv, a1 = p1 * inv;

    // weighted intent wI[o] = sum_n alpha_n I[n][o] (fp32, m-lane reduce)
    float wi[16];
#pragma unroll
    for (int om = 0; om < 4; ++om)
#pragma unroll
        for (int r = 0; r < 4; ++r)
            wi[om * 4 + r] = a0 * I[om][0][r] + a1 * I[om][1][r];
#pragma unroll
    for (int idx = 0; idx < 16; ++idx) {
#pragma unroll
        for (int msk = 1; msk <= 8; msk <<= 1)
            wi[idx] += __shfl_xor(wi[idx], msk);
    }

    // out[b][j]: lane (g,m) dots its o-subset for j=m, then g-reduce
    float val = 0.f;
#pragma unroll
    for (int idx = 0; idx < 16; ++idx)
        val = fmaf(wi[idx], Wvof[lane * 16 + idx], val);
    val += __shfl_xor(val, 16);
    val += __shfl_xor(val, 32);

    if (lane < 16) out[(size_t)b * 16 + lane] = val + bvo[lane];
}

// ---------------------------------------------------------------------------
extern "C" void kernel_launch(void* const* d_in, const int* in_sizes, int n_in,
                              void* d_out, int out_size, void* d_ws, size_t ws_size,
                              hipStream_t stream) {
    const float* self_obs = (const float*)d_in[0];
    const float* nbr      = (const float*)d_in[1];
    const float* ew       = (const float*)d_in[2];
    const float* W1       = (const float*)d_in[3];
    const float* b1       = (const float*)d_in[4];
    const float* W2       = (const float*)d_in[5];
    const float* b2       = (const float*)d_in[6];
    const float* Wa       = (const float*)d_in[7];
    const float* ba       = (const float*)d_in[8];
    const float* Wv       = (const float*)d_in[9];
    const float* bv       = (const float*)d_in[10];
    const float* Wo       = (const float*)d_in[11];
    const float* bo       = (const float*)d_in[12];
    char* ws = (char*)d_ws;
    float* out = (float*)d_out;

    prep_kernel<<<93, 256, 0, stream>>>(W1, b1, W2, Wv, Wa, Wo, bv, bo, ws);
    self_kernel<<<64, 512, 0, stream>>>(self_obs, b2, ws);
    main_kernel<<<2048, 512, 0, stream>>>(nbr, ew, b2, ba, ws, out);
}